// Round 7
// baseline (116.599 us; speedup 1.0000x reference)
//
#include <hip/hip_runtime.h>

typedef __attribute__((ext_vector_type(4))) float f32x4;
typedef __attribute__((ext_vector_type(8))) short short8;

#define EPSF 1e-12f

__device__ __forceinline__ ushort bf16rne(float x) {
  uint u = __float_as_uint(x);
  u += 0x7fffu + ((u >> 16) & 1u);
  return (ushort)(u >> 16);
}
__device__ __forceinline__ float bf2f(ushort h) {
  return __uint_as_float(((uint)h) << 16);
}
__device__ __forceinline__ uint cvtpk(float lo, float hi) {
  uint r;
  asm("v_cvt_pk_bf16_f32 %0, %1, %2" : "=v"(r) : "v"(lo), "v"(hi));
  return r;
}
union US8 { uint4 u; short8 s; };
// 8 floats -> hi/lo bf16 short8 pair via packed converts (RNE, identical to
// bf16rne split: hi = RNE(v), lo = RNE(v - hi))
__device__ __forceinline__ void cvt8hl(float4 v0, float4 v1, short8& h8, short8& l8) {
  US8 h, l;
  h.u.x = cvtpk(v0.x, v0.y);
  h.u.y = cvtpk(v0.z, v0.w);
  h.u.z = cvtpk(v1.x, v1.y);
  h.u.w = cvtpk(v1.z, v1.w);
  float r0 = __uint_as_float(h.u.x << 16), r1 = __uint_as_float(h.u.x & 0xffff0000u);
  float r2 = __uint_as_float(h.u.y << 16), r3 = __uint_as_float(h.u.y & 0xffff0000u);
  float r4 = __uint_as_float(h.u.z << 16), r5 = __uint_as_float(h.u.z & 0xffff0000u);
  float r6 = __uint_as_float(h.u.w << 16), r7 = __uint_as_float(h.u.w & 0xffff0000u);
  l.u.x = cvtpk(v0.x - r0, v0.y - r1);
  l.u.y = cvtpk(v0.z - r2, v0.w - r3);
  l.u.z = cvtpk(v1.x - r4, v1.y - r5);
  l.u.w = cvtpk(v1.z - r6, v1.w - r7);
  h8 = h.s;
  l8 = l.s;
}
__device__ __forceinline__ f32x4 mfma16(short8 a, short8 b, f32x4 c) {
  return __builtin_amdgcn_mfma_f32_16x16x32_bf16(a, b, c, 0, 0, 0);
}

// ---------------------------------------------------------------------------
// K0: W [512][64] f32 -> W^T bf16 hi/lo in ws: [2][64 k][512 d]
// ---------------------------------------------------------------------------
__global__ __launch_bounds__(256) void k0_wt(const float* __restrict__ W,
                                             ushort* __restrict__ wsWT) {
  int k = blockIdx.x;  // 64
  for (int d = threadIdx.x; d < 512; d += 256) {
    float v = W[(size_t)d * 64 + k];
    ushort h = bf16rne(v);
    wsWT[k * 512 + d] = h;
    wsWT[32768 + k * 512 + d] = bf16rne(v - bf2f(h));
  }
}

// ---------------------------------------------------------------------------
// K1: per (n, r, third of 48 pixels): s^T = W^T * x with ALL MFMA fragments
// loaded directly global->register (no LDS staging, no barriers in d-loop):
//   A-frag: W^T bf16 hi/lo straight from ws (pre-converted by k0, L2-hot)
//   B-frag: x f32 -> cvt_pk bf16 hi/lo in-register; per-lane base + imm offs
// Then softmax over k (cross-wave LDS reduce) and a^T dump as before.
// ---------------------------------------------------------------------------
__global__ __launch_bounds__(256, 4) void k1_assign(
    const float* __restrict__ x, const ushort* __restrict__ wsWT,
    float4* __restrict__ aT_ws, float* __restrict__ asum_ws) {
  __shared__ char sm[15872];
  ushort* atH = (ushort*)sm;              // [64 k][56-pad p]
  ushort* atL = (ushort*)(sm + 7168);
  float* smax = (float*)(sm + 14336);     // [4 w][48 p]
  float* ssum = (float*)(sm + 15104);

  int b = blockIdx.x;          // 864
  int region = b / 3, third = b % 3;
  int n = region / 9, r = region % 9;
  int y1 = (r / 3) * 12, x1 = (r % 3) * 12;
  int p0 = third * 48;
  int t = threadIdx.x;
  int w = t >> 6;
  int lane = t & 63, l15 = lane & 15, hi16 = lane >> 4;
  const float* xn = x + (size_t)n * (36 * 36 * 512);

  // per-lane fragment base pointers (d-offset folds into imm)
  const float* pb0;
  const float* pb1;
  const float* pb2;
  {
    int pr0 = p0 + 0 * 16 + l15;
    int pr1 = p0 + 1 * 16 + l15;
    int pr2 = p0 + 2 * 16 + l15;
    pb0 = xn + ((size_t)(y1 + pr0 / 12) * 36 + (x1 + pr0 % 12)) * 512 + hi16 * 8;
    pb1 = xn + ((size_t)(y1 + pr1 / 12) * 36 + (x1 + pr1 % 12)) * 512 + hi16 * 8;
    pb2 = xn + ((size_t)(y1 + pr2 / 12) * 36 + (x1 + pr2 % 12)) * 512 + hi16 * 8;
  }
  const ushort* aBaseH = wsWT + (w * 16 + l15) * 512 + hi16 * 8;
  const ushort* aBaseL = aBaseH + 32768;

  f32x4 acc[3];
#pragma unroll
  for (int ni = 0; ni < 3; ++ni) acc[ni] = (f32x4){0.f, 0.f, 0.f, 0.f};

#pragma unroll
  for (int c = 0; c < 8; ++c) {
#pragma unroll
    for (int ks = 0; ks < 2; ++ks) {
      const int off = c * 64 + ks * 32;   // compile-time (fully unrolled)
      short8 aH = *(const short8*)(aBaseH + off);
      short8 aL = *(const short8*)(aBaseL + off);
      {
        float4 v0 = *(const float4*)(pb0 + off);
        float4 v1 = *(const float4*)(pb0 + off + 4);
        short8 bH, bL;
        cvt8hl(v0, v1, bH, bL);
        f32x4 a0 = acc[0];
        a0 = mfma16(aH, bH, a0);
        a0 = mfma16(aH, bL, a0);
        a0 = mfma16(aL, bH, a0);
        acc[0] = a0;
      }
      {
        float4 v0 = *(const float4*)(pb1 + off);
        float4 v1 = *(const float4*)(pb1 + off + 4);
        short8 bH, bL;
        cvt8hl(v0, v1, bH, bL);
        f32x4 a0 = acc[1];
        a0 = mfma16(aH, bH, a0);
        a0 = mfma16(aH, bL, a0);
        a0 = mfma16(aL, bH, a0);
        acc[1] = a0;
      }
      {
        float4 v0 = *(const float4*)(pb2 + off);
        float4 v1 = *(const float4*)(pb2 + off + 4);
        short8 bH, bL;
        cvt8hl(v0, v1, bH, bL);
        f32x4 a0 = acc[2];
        a0 = mfma16(aH, bH, a0);
        a0 = mfma16(aH, bL, a0);
        a0 = mfma16(aL, bH, a0);
        acc[2] = a0;
      }
    }
  }

  // ---- softmax over k (cross-wave: each wave holds 16 k's of every p) ----
  // acc[ni][rr] = s[k = w*16 + hi16*4 + rr][p = ni*16 + l15]
  float lm[3];
#pragma unroll
  for (int ni = 0; ni < 3; ++ni) {
    float m = fmaxf(fmaxf(acc[ni][0], acc[ni][1]), fmaxf(acc[ni][2], acc[ni][3]));
    m = fmaxf(m, __shfl_xor(m, 16));
    m = fmaxf(m, __shfl_xor(m, 32));
    lm[ni] = m;
  }
  if (hi16 == 0)
#pragma unroll
    for (int ni = 0; ni < 3; ++ni) smax[w * 48 + ni * 16 + l15] = lm[ni];
  __syncthreads();

  float e[3][4], ls[3];
#pragma unroll
  for (int ni = 0; ni < 3; ++ni) {
    int p = ni * 16 + l15;
    float M = fmaxf(fmaxf(smax[0 * 48 + p], smax[1 * 48 + p]),
                    fmaxf(smax[2 * 48 + p], smax[3 * 48 + p]));
    float s = 0.f;
#pragma unroll
    for (int rr = 0; rr < 4; ++rr) {
      e[ni][rr] = __expf(acc[ni][rr] - M);
      s += e[ni][rr];
    }
    s += __shfl_xor(s, 16);
    s += __shfl_xor(s, 32);
    ls[ni] = s;
  }
  if (hi16 == 0)
#pragma unroll
    for (int ni = 0; ni < 3; ++ni) ssum[w * 48 + ni * 16 + l15] = ls[ni];
  __syncthreads();

  float part[4];
#pragma unroll
  for (int rr = 0; rr < 4; ++rr) part[rr] = 0.f;

#pragma unroll
  for (int ni = 0; ni < 3; ++ni) {
    int p = ni * 16 + l15;
    float S = ssum[0 * 48 + p] + ssum[1 * 48 + p] + ssum[2 * 48 + p] + ssum[3 * 48 + p];
    float inv = 1.f / S;
#pragma unroll
    for (int rr = 0; rr < 4; ++rr) {
      float a = e[ni][rr] * inv;
      part[rr] += a;
      int k = w * 16 + hi16 * 4 + rr;
      ushort h = bf16rne(a);
      atH[k * 56 + p] = h;
      atL[k * 56 + p] = bf16rne(a - bf2f(h));
    }
  }
  // asum reduce over l15 -> slot per (block, k)
#pragma unroll
  for (int rr = 0; rr < 4; ++rr) {
    float s = part[rr];
    s += __shfl_xor(s, 1);
    s += __shfl_xor(s, 2);
    s += __shfl_xor(s, 4);
    s += __shfl_xor(s, 8);
    if (l15 == 0) asum_ws[b * 64 + w * 16 + hi16 * 4 + rr] = s;
  }
  __syncthreads();  // a^T LDS writes done

  // dump a^T to region slot [2][64][19 f4] at granule cols third*6..+5
  {
    float4* dst = aT_ws + (size_t)region * 2432;
    for (int i = t; i < 768; i += 256) {
      int plane = i / 384;
      int rem = i - plane * 384;
      int row = rem / 6, c4 = rem - row * 6;
      float4 v = *(const float4*)(sm + plane * 7168 + row * 112 + c4 * 16);
      dst[plane * 1216 + row * 19 + third * 6 + c4] = v;
    }
    if (third == 2) {
      float4 z = {0.f, 0.f, 0.f, 0.f};
      for (int i = t; i < 128; i += 256) {
        int plane = i >> 6, row = i & 63;
        dst[plane * 1216 + row * 19 + 18] = z;
      }
    }
  }
}

// ---------------------------------------------------------------------------
// K2: per (n,r,dc of 64): V = X^T * A - C*asum.
// A-frags (x^T) loaded DIRECTLY global->register (transposed addressing via
// LDS poff table); B-frags (a^T) from linear-copied padded-152 LDS.
// colnorm^2 written to a private (reg,dc) slot — no atomics, no memset.
// ---------------------------------------------------------------------------
__global__ __launch_bounds__(512, 8) void k2_vlad(
    const float* __restrict__ x, const float* __restrict__ C,
    const float4* __restrict__ aT_ws, const float* __restrict__ asum_ws,
    float* __restrict__ out, float* __restrict__ colnorm) {
  __shared__ float4 smv[2504];               // 40064 B
  char* sm = (char*)smv;
  ushort* atH = (ushort*)sm;                 // [64 k][152 p]
  ushort* atL = (ushort*)(sm + 19456);
  int* poff = (int*)(sm + 38912);            // [160] pixel offsets (elements)
  float* asumS = (float*)(sm + 39552);
  float* cn2 = (float*)(sm + 39808);

  int b = blockIdx.x;          // 2304
  int reg = b % 288;           // XCD-swizzle: all 8 dc of a region -> same XCD
  int dc = b / 288;
  int n = reg / 9, r = reg % 9;
  int d0 = dc * 64;
  int y1 = (r / 3) * 12, x1 = (r % 3) * 12;
  int t = threadIdx.x;
  int w = t >> 6, lane = t & 63, l15 = lane & 15, hi16 = lane >> 4;
  const float* xn = x + (size_t)n * (36 * 36 * 512);

  if (t < 160) poff[t] = (t < 144) ? ((y1 + t / 12) * 36 + (x1 + t % 12)) * 512 : 0;
  if (t < 64) {
    asumS[t] = asum_ws[(reg * 3) * 64 + t] + asum_ws[(reg * 3 + 1) * 64 + t] +
               asum_ws[(reg * 3 + 2) * 64 + t];
    cn2[t] = 0.f;
  }
  {
    const float4* src = aT_ws + (size_t)reg * 2432;
    for (int i = t; i < 2432; i += 512) smv[i] = src[i];
  }
  __syncthreads();

  int mi = w & 3, kh = w >> 2;
  int drow = d0 + mi * 16 + l15;
  const float* xcol = xn + drow;

  f32x4 acc[2];
  acc[0] = (f32x4){0.f, 0.f, 0.f, 0.f};
  acc[1] = (f32x4){0.f, 0.f, 0.f, 0.f};

#pragma unroll
  for (int ks = 0; ks < 5; ++ks) {
    int pb = ks * 32 + hi16 * 8;
    int4 poA = *reinterpret_cast<const int4*>(&poff[pb]);
    int4 poB = *reinterpret_cast<const int4*>(&poff[pb + 4]);
    bool valid = (ks < 4) || (hi16 < 2);   // p >= 144 -> zero A (kills product)
    float4 u0, u1;
    u0.x = valid ? xcol[poA.x] : 0.f;
    u0.y = valid ? xcol[poA.y] : 0.f;
    u0.z = valid ? xcol[poA.z] : 0.f;
    u0.w = valid ? xcol[poA.w] : 0.f;
    u1.x = valid ? xcol[poB.x] : 0.f;
    u1.y = valid ? xcol[poB.y] : 0.f;
    u1.z = valid ? xcol[poB.z] : 0.f;
    u1.w = valid ? xcol[poB.w] : 0.f;
    short8 ah, al;
    cvt8hl(u0, u1, ah, al);
#pragma unroll
    for (int ni = 0; ni < 2; ++ni) {
      int row = kh * 32 + ni * 16 + l15;
      short8 bh = *(const short8*)(atH + row * 152 + pb);
      short8 bl = *(const short8*)(atL + row * 152 + pb);
      f32x4 a0 = acc[ni];
      a0 = mfma16(ah, bh, a0);
      a0 = mfma16(ah, bl, a0);
      a0 = mfma16(al, bh, a0);
      acc[ni] = a0;
    }
  }

  size_t obase = (size_t)reg * (512 * 64);
#pragma unroll
  for (int ni = 0; ni < 2; ++ni) {
    int k = kh * 32 + ni * 16 + l15;
    float ak = asumS[k];
    float s2 = 0.f;
#pragma unroll
    for (int rr = 0; rr < 4; ++rr) {
      int d = d0 + mi * 16 + hi16 * 4 + rr;
      float v = acc[ni][rr] - C[(size_t)d * 64 + k] * ak;
      out[obase + (size_t)d * 64 + k] = v;
      s2 += v * v;
    }
    atomicAdd(&cn2[k], s2);
  }
  __syncthreads();
  if (t < 64) colnorm[(size_t)(reg * 8 + dc) * 64 + t] = cn2[t];
}

// ---------------------------------------------------------------------------
// K3: intra-norm + global-norm scaling in place (sums 8 partial colnorms).
// ---------------------------------------------------------------------------
__global__ __launch_bounds__(256) void k3_scale(float* __restrict__ out,
                                                const float* __restrict__ colnorm) {
  int b = blockIdx.x;  // 1152
  int reg = b % 288;   // match k2's writer XCD for L2 reuse
  int dc = b / 288;

  __shared__ float ratio[64];
  __shared__ float fs[64];
  int t = threadIdx.x;
  float c = 0.f;
  if (t < 64) {
#pragma unroll
    for (int j = 0; j < 8; ++j) c += colnorm[(size_t)(reg * 8 + j) * 64 + t];
    ratio[t] = c / (c + EPSF);
  }
  __syncthreads();
  if (t < 64) {
    float g = 0.f;
#pragma unroll
    for (int j = 0; j < 64; ++j) g += ratio[j];
    fs[t] = rsqrtf(c + EPSF) * rsqrtf(g + EPSF);
  }
  __syncthreads();

  size_t base4 = (((size_t)reg * 512) + (size_t)dc * 128) * 64 / 4;
  float4* o4 = reinterpret_cast<float4*>(out);
  for (int j = 0; j < 8; ++j) {
    size_t idx = base4 + t + 256 * j;
    float4 v = o4[idx];
    int k0 = (int)((idx * 4) & 63);
    v.x *= fs[k0]; v.y *= fs[k0 + 1]; v.z *= fs[k0 + 2]; v.w *= fs[k0 + 3];
    o4[idx] = v;
  }
}

extern "C" void kernel_launch(void* const* d_in, const int* in_sizes, int n_in,
                              void* d_out, int out_size, void* d_ws, size_t ws_size,
                              hipStream_t stream) {
  const float* x = (const float*)d_in[0];   // [32,36,36,512]
  const float* Wc = (const float*)d_in[1];  // [512,64]
  const float* C = (const float*)d_in[2];   // [512,64]
  float* out = (float*)d_out;

  char* ws = (char*)d_ws;
  ushort* wsWT = (ushort*)(ws);             // 131072 B
  float* asum_ws = (float*)(ws + 131072);   // 864*64*4 = 221184 B
  float* colnorm = (float*)(ws + 352256);   // 2304*64*4 = 589824 B
  float4* aT_ws = (float4*)(ws + 942080);   // 288 * 38912 B = 11.2 MB

  k0_wt<<<64, 256, 0, stream>>>(Wc, wsWT);
  k1_assign<<<864, 256, 0, stream>>>(x, wsWT, aT_ws, asum_ws);
  k2_vlad<<<2304, 512, 0, stream>>>(x, C, aT_ws, asum_ws, out, colnorm);
  k3_scale<<<1152, 256, 0, stream>>>(out, colnorm);
}